// Round 5
// baseline (1129.509 us; speedup 1.0000x reference)
//
#include <hip/hip_runtime.h>
#include <cmath>

// Problem constants
#define Bb 256
#define Ss 50
#define Cc 40
#define Dd 256
#define Vv 20000

typedef __bf16 bf16;
typedef __bf16 bf16x8 __attribute__((ext_vector_type(8)));
typedef float f32x4 __attribute__((ext_vector_type(4)));

#define GL2LDS(g, l) __builtin_amdgcn_global_load_lds( \
    (__attribute__((address_space(1))) void*)(g), \
    (__attribute__((address_space(3))) void*)(l), 16, 0, 0)

// ---------------- ws layout (BYTE offsets) ----------------
// gates bf16 (12800x1024) @0 (26MB); embb bf16 @0 dead after embed;
// after recurrence the region is reused by aligned/cat/tmp/H1/attnw.
#define OFFB_GATES    0ull
#define OFFB_EMBB     0ull
#define OFFB_ALIGNED  0ull
#define OFFB_CAT      13107200ull
#define OFFB_TMPB     25952256ull
#define OFFB_H1       32505856ull
#define OFFB_ATTNW    35717120ull
#define OFFB_X        52428800ull
#define OFFB_XB       65536000ull
#define OFFB_RNNB     72089600ull
#define OFFB_W        78643200ull
#define OFFB_WIHB     92012544ull
#define OFFB_WHHB     92536832ull
#define OFFB_WHKB     93061120ull
#define OFFB_W1B      93192192ull
#define OFFB_WDTB     93257728ull
#define OFFB_SALPHA   93388800ull
#define OFFB_SBETA    93389824ull

__device__ __forceinline__ float fsig(float x) {
    return __fdividef(1.f, 1.f + __expf(-x));
}
__device__ __forceinline__ float ftanh(float x) {
    return 2.f * fsig(2.f * x) - 1.f;
}

// ---------------- bf16 MFMA GEMM ----------------
// OBF==1: store output as bf16 (else fp32)
template<int BM, int BN, int ACT, int OBF>
__global__ __launch_bounds__(256) void mfma_gemm(
    const bf16* __restrict__ A, int lda,
    const bf16* __restrict__ B, int ldb,
    const float* __restrict__ bias1, const float* __restrict__ bias2,
    void* __restrict__ Cv, int ldc, int K)
{
    constexpr int BK = 32;
    constexpr int NF = BN / 32;
    __shared__ bf16 As[BM * BK];
    __shared__ bf16 Bs[BN * BK];
    const int tid  = threadIdx.x;
    const int wave = tid >> 6;
    const int lane = tid & 63;
    const int m0 = blockIdx.x * BM;
    const int n0 = blockIdx.y * BN;
    const int wm = (wave >> 1) * 64;
    const int wn = (wave & 1) * (BN / 2);

    f32x4 acc[4][NF];
#pragma unroll
    for (int i = 0; i < 4; ++i)
#pragma unroll
        for (int j = 0; j < NF; ++j) acc[i][j] = (f32x4){0.f, 0.f, 0.f, 0.f};

    const int ar = tid >> 2;
    const int ac = tid & 3;
    const int sw = ac ^ (ar & 3);
    const int lr = lane & 15;
    const int q  = lane >> 4;

    for (int k0 = 0; k0 < K; k0 += BK) {
        __syncthreads();
#pragma unroll
        for (int it = 0; it < BM / 64; ++it) {
            const bf16* gp = A + (size_t)(m0 + it * 64 + ar) * lda + k0 + sw * 8;
            GL2LDS(gp, As + it * 2048 + wave * 512);
        }
#pragma unroll
        for (int it = 0; it < BN / 64; ++it) {
            const bf16* gp = B + (size_t)(n0 + it * 64 + ar) * ldb + k0 + sw * 8;
            GL2LDS(gp, Bs + it * 2048 + wave * 512);
        }
        __syncthreads();

        bf16x8 af[4], bfv[NF];
#pragma unroll
        for (int fm = 0; fm < 4; ++fm) {
            int m = wm + fm * 16 + lr;
            af[fm] = *(const bf16x8*)(As + m * 32 + ((q ^ (m & 3)) * 8));
        }
#pragma unroll
        for (int fn = 0; fn < NF; ++fn) {
            int n = wn + fn * 16 + lr;
            bfv[fn] = *(const bf16x8*)(Bs + n * 32 + ((q ^ (n & 3)) * 8));
        }
#pragma unroll
        for (int fm = 0; fm < 4; ++fm)
#pragma unroll
            for (int fn = 0; fn < NF; ++fn)
                acc[fm][fn] = __builtin_amdgcn_mfma_f32_16x16x32_bf16(
                    af[fm], bfv[fn], acc[fm][fn], 0, 0, 0);
    }

    const int rbase = q * 4;
#pragma unroll
    for (int fn = 0; fn < NF; ++fn) {
        const int col = n0 + wn + fn * 16 + lr;
        float bb = 0.f;
        if (bias1) bb += bias1[col];
        if (bias2) bb += bias2[col];
#pragma unroll
        for (int fm = 0; fm < 4; ++fm) {
            f32x4 v = acc[fm][fn];
#pragma unroll
            for (int r = 0; r < 4; ++r) {
                const int row = m0 + wm + fm * 16 + rbase + r;
                float val = v[r] + bb;
                if (ACT == 1) val = tanhf(val);
                if (OBF)
                    ((bf16*)Cv)[(size_t)row * ldc + col] = (bf16)val;
                else
                    ((float*)Cv)[(size_t)row * ldc + col] = val;
            }
        }
    }
}

// ---------------- LSTM recurrence: 16 independent blocks, 1 launch -------
// Low-register-pressure rework of R4 (which spilled: 170+ live regs vs 128
// allocated, per-kc vmcnt(0) drains from the bcur=bnxt copies → 9us/step).
// A-fragments hoisted (loaded once/step from LDS), per-gate transient B
// loads (no double-buffer copies), preacts prefetched as bf16, fast
// sigmoid/tanh via v_exp_f32. Zero cross-block communication.
__global__ __launch_bounds__(512, 2) void lstm_rec(
    const bf16* __restrict__ Whhb,    // (1024 x 256) N x K
    const bf16* __restrict__ gatesb,  // (B*S x 1024) x@Wih^T+bih+bhh (bf16)
    bf16* __restrict__ rnnb)          // (B*S x 256) h outputs
{
    __shared__ bf16 hb[2][16][264];
    const int tid  = threadIdx.x;
    const int w    = tid >> 6;
    const int lane = tid & 63;
    const int lr   = lane & 15;
    const int q    = lane >> 4;
    const int bm   = blockIdx.x;
    const int wbase = w * 32;

    for (int i = tid; i < 16 * 264; i += 512)
        hb[0][i / 264][i % 264] = (bf16)0.f;

    // element offsets into Whhb for the 8 B-tiles (32-bit: sgpr base + voffset)
    int boff[4][2];
#pragma unroll
    for (int g = 0; g < 4; ++g)
#pragma unroll
        for (int j = 0; j < 2; ++j)
            boff[g][j] = (g * 256 + wbase + j * 16 + lr) * 256 + q * 8;

    // preact element base per r: row bm*16+q*4+r, col wbase+lr (+g*256+j*16)
    int grow[4];
#pragma unroll
    for (int r = 0; r < 4; ++r)
        grow[r] = ((bm * 16 + q * 4 + r) * Ss) * 1024 + wbase + lr;

    float c[2][4];
#pragma unroll
    for (int j = 0; j < 2; ++j)
#pragma unroll
        for (int r = 0; r < 4; ++r) c[j][r] = 0.f;

    __syncthreads();

    for (int t = 0; t < Ss; ++t) {
        const int p = t & 1;

        // prefetch this lane's 32 gate pre-activations (bf16, h-independent)
        bf16 pg[4][2][4];
#pragma unroll
        for (int r = 0; r < 4; ++r) {
            const bf16* gp = gatesb + grow[r] + t * 1024;
#pragma unroll
            for (int g = 0; g < 4; ++g)
#pragma unroll
                for (int j = 0; j < 2; ++j)
                    pg[g][j][r] = gp[g * 256 + j * 16];
        }

        f32x4 acc[4][2];
#pragma unroll
        for (int g = 0; g < 4; ++g)
#pragma unroll
            for (int j = 0; j < 2; ++j) acc[g][j] = (f32x4){0.f, 0.f, 0.f, 0.f};

        if (t > 0) {
            // A fragments once (shared by all 8 tiles)
            bf16x8 a[8];
#pragma unroll
            for (int kc = 0; kc < 8; ++kc)
                a[kc] = *(const bf16x8*)&hb[p][lr][kc * 32 + q * 8];
            // per-gate transient B loads from L2
#pragma unroll
            for (int g = 0; g < 4; ++g) {
#pragma unroll
                for (int kc = 0; kc < 8; ++kc) {
                    bf16x8 b0 = *(const bf16x8*)(Whhb + boff[g][0] + kc * 32);
                    bf16x8 b1 = *(const bf16x8*)(Whhb + boff[g][1] + kc * 32);
                    acc[g][0] = __builtin_amdgcn_mfma_f32_16x16x32_bf16(
                        a[kc], b0, acc[g][0], 0, 0, 0);
                    acc[g][1] = __builtin_amdgcn_mfma_f32_16x16x32_bf16(
                        a[kc], b1, acc[g][1], 0, 0, 0);
                }
            }
        }

        // gate math: lane-local across the 8 acc tiles
#pragma unroll
        for (int j = 0; j < 2; ++j)
#pragma unroll
            for (int r = 0; r < 4; ++r) {
                float gi = acc[0][j][r] + (float)pg[0][j][r];
                float gf = acc[1][j][r] + (float)pg[1][j][r];
                float gg = acc[2][j][r] + (float)pg[2][j][r];
                float go = acc[3][j][r] + (float)pg[3][j][r];
                float ii = fsig(gi);
                float ff = fsig(gf);
                float g2 = ftanh(gg);
                float oo = fsig(go);
                c[j][r] = ff * c[j][r] + ii * g2;
                float h = oo * ftanh(c[j][r]);
                const int m = q * 4 + r;
                const int d = wbase + j * 16 + lr;
                bf16 hv = (bf16)h;
                hb[p ^ 1][m][d] = hv;
                rnnb[((size_t)(bm * 16 + m) * Ss + t) * Dd + d] = hv;
            }
        __syncthreads();
    }
}

// ---------------- weight converts (one launch) ----------------
__global__ __launch_bounds__(256) void cvt_weights_kernel(
    const float* __restrict__ Wih, const float* __restrict__ Whh,
    const float* __restrict__ Whk, const float* __restrict__ W1,
    bf16* __restrict__ Wihb, bf16* __restrict__ Whhb,
    bf16* __restrict__ Whkb, bf16* __restrict__ W1b)
{
    int i = blockIdx.x * 256 + threadIdx.x;   // float4 index
    const float* src; bf16* dst; int base;
    if (i < 65536)       { src = Wih; dst = Wihb; base = 0; }
    else if (i < 131072) { src = Whh; dst = Whhb; base = 65536; }
    else if (i < 147456) { src = Whk; dst = Whkb; base = 131072; }
    else                 { src = W1;  dst = W1b;  base = 147456; }
    int j = i - base;
    float4 v = *((const float4*)src + j);
    bf16* o = dst + j * 4;
    o[0] = (bf16)v.x; o[1] = (bf16)v.y; o[2] = (bf16)v.z; o[3] = (bf16)v.w;
}

__global__ __launch_bounds__(256) void cvt_emb_kernel(
    const float* __restrict__ src, bf16* __restrict__ dst, int n4)
{
    int i = blockIdx.x * 256 + threadIdx.x;
    if (i >= n4) return;
    float4 v = *((const float4*)src + i);
    bf16* o = dst + i * 4;
    o[0] = (bf16)v.x; o[1] = (bf16)v.y; o[2] = (bf16)v.z; o[3] = (bf16)v.w;
}

__global__ __launch_bounds__(256) void transpose_cvt_kernel(
    const float* __restrict__ in, bf16* __restrict__ out, int R, int C)
{
    __shared__ float t[32][33];
    const int c0 = blockIdx.x * 32, r0 = blockIdx.y * 32;
    const int tx = threadIdx.x & 31, ty = threadIdx.x >> 5;
    for (int i = ty; i < 32; i += 8)
        t[i][tx] = in[(size_t)(r0 + i) * C + c0 + tx];
    __syncthreads();
    for (int i = ty; i < 32; i += 8)
        out[(size_t)(c0 + i) * R + r0 + tx] = (bf16)t[tx][i];
}

// ---------------- per-batch diffusion scale factors ----------------
__global__ void alpha_kernel(const int* __restrict__ tdiff,
                             float* __restrict__ salpha, float* __restrict__ sbeta)
{
    const int b = threadIdx.x;
    const int t = tdiff[b];
    const float step = (0.02f - 1e-4f) / 999.f;
    float prod = 1.f;
    for (int j = 0; j <= t; ++j) prod *= (1.f - (1e-4f + j * step));
    salpha[b] = sqrtf(prod);
    sbeta[b]  = sqrtf(fmaxf(1.f - prod, 0.f));
}

// ---------------- embedding gather-sum from bf16 table ----------------
__global__ __launch_bounds__(128) void embed_kernel(
    const int* __restrict__ seqs, const unsigned* __restrict__ emb2,
    float* __restrict__ x, bf16* __restrict__ xb)
{
    __shared__ int idx[Cc];
    const int bs = blockIdx.x;
    const int tid = threadIdx.x;
    if (tid < Cc) idx[tid] = seqs[(size_t)bs * Cc + tid];
    __syncthreads();
    float s0 = 0.f, s1 = 0.f;
#pragma unroll 8
    for (int c = 0; c < Cc; ++c) {
        unsigned u = emb2[(size_t)idx[c] * 128 + tid];
        union { unsigned ui; float f; } lo, hi;
        lo.ui = u << 16;
        hi.ui = u & 0xffff0000u;
        s0 += lo.f;
        s1 += hi.f;
    }
    ((float2*)x)[(size_t)bs * 128 + tid] = make_float2(s0, s1);
    union { bf16 h[2]; unsigned u; } pk;
    pk.h[0] = (bf16)s0; pk.h[1] = (bf16)s1;
    ((unsigned*)xb)[(size_t)bs * 128 + tid] = pk.u;
}

// ---------------- attention: cat build (bf16), logits, apply ----------------
__global__ __launch_bounds__(256) void cat_build_kernel(
    const float* __restrict__ x, const float* __restrict__ w, bf16* __restrict__ cat)
{
    const int r = blockIdx.x;             // b*49+t
    const int b = r / (Ss - 1), t = r % (Ss - 1);
    const int d = threadIdx.x;
    cat[(size_t)r * 512 + d]       = (bf16)x[((size_t)b * Ss) * Dd + d];
    cat[(size_t)r * 512 + 256 + d] = (bf16)w[((size_t)b * Ss + t) * Dd + d];
}

__global__ __launch_bounds__(256) void attn2_kernel(
    const float* __restrict__ H1, const float* __restrict__ W2,
    const float* __restrict__ b2, float* __restrict__ attnw)
{
    const int r = blockIdx.x * 4 + (threadIdx.x >> 6);
    const int j = threadIdx.x & 63;
    float h = H1[(size_t)r * 64 + j];
    float v0 = h * W2[j];
    float v1 = h * W2[64 + j];
#pragma unroll
    for (int off = 32; off; off >>= 1) { v0 += __shfl_down(v0, off); v1 += __shfl_down(v1, off); }
    if (j == 0) {
        float z0 = v0 + b2[0], z1 = v1 + b2[1];
        float m = fmaxf(z0, z1);
        float e0 = expf(z0 - m), e1 = expf(z1 - m);
        float inv = 1.f / (e0 + e1);
        attnw[(size_t)r * 2 + 0] = e0 * inv;
        attnw[(size_t)r * 2 + 1] = e1 * inv;
    }
}

__global__ __launch_bounds__(256) void attn_apply_kernel(
    const float* __restrict__ x, const float* __restrict__ w,
    const float* __restrict__ attnw, float* __restrict__ aligned)
{
    const int bs = blockIdx.x;
    const int b = bs / Ss, s = bs % Ss;
    const int d = threadIdx.x;
    const float ek = x[((size_t)b * Ss) * Dd + d];
    float v;
    if (s == 0) {
        v = ek;
    } else {
        const int r = b * (Ss - 1) + (s - 1);
        const float a0 = attnw[(size_t)r * 2], a1 = attnw[(size_t)r * 2 + 1];
        v = ek * a0 + w[((size_t)b * Ss + s - 1) * Dd + d] * a1;
    }
    aligned[(size_t)bs * Dd + d] = v;
}

// ---------------- diffusion elementwise + noise passthrough ----------------
__global__ __launch_bounds__(256) void diff_kernel(
    const float* __restrict__ aligned, const float* __restrict__ noise,
    const float* __restrict__ temb, const int* __restrict__ tdiff,
    const float* __restrict__ salpha, const float* __restrict__ sbeta,
    bf16* __restrict__ tmpb, float* __restrict__ noise_out)
{
    const int bs = blockIdx.x;
    const int b = bs / Ss;
    const int d = threadIdx.x;
    const size_t i = (size_t)bs * Dd + d;
    const int t = tdiff[b];
    const float nz = noise[i];
    tmpb[i] = (bf16)(aligned[i] * salpha[b] + nz * sbeta[b] + temb[(size_t)t * Dd + d]);
    noise_out[i] = nz;
}

// ---------------- pooled 2-class heads ----------------
__device__ inline void pool_reduce_write(float m, const float* __restrict__ Wout,
                                         const float* __restrict__ bout,
                                         float* __restrict__ outp, int b,
                                         float* r0, float* r1)
{
    float v0 = m * Wout[threadIdx.x];
    float v1 = m * Wout[Dd + threadIdx.x];
#pragma unroll
    for (int off = 32; off; off >>= 1) { v0 += __shfl_down(v0, off); v1 += __shfl_down(v1, off); }
    const int lane = threadIdx.x & 63, wv = threadIdx.x >> 6;
    if (lane == 0) { r0[wv] = v0; r1[wv] = v1; }
    __syncthreads();
    if (threadIdx.x == 0) {
        outp[b * 2 + 0] = r0[0] + r0[1] + r0[2] + r0[3] + bout[0];
        outp[b * 2 + 1] = r1[0] + r1[1] + r1[2] + r1[3] + bout[1];
    }
}

__global__ __launch_bounds__(256) void pool_x_kernel(
    const float* __restrict__ x, const float* __restrict__ Wout,
    const float* __restrict__ bout, float* __restrict__ outp)
{
    __shared__ float r0[4], r1[4];
    const int b = blockIdx.x, d = threadIdx.x;
    float m = -INFINITY;
    for (int s = 0; s < Ss; ++s) m = fmaxf(m, x[((size_t)b * Ss + s) * Dd + d]);
    pool_reduce_write(m, Wout, bout, outp, b, r0, r1);
}

__global__ __launch_bounds__(256) void gen_pool_kernel(
    const float* __restrict__ aligned, const float* __restrict__ noise,
    const float* __restrict__ pred, const float* __restrict__ Wout,
    const float* __restrict__ bout, float* __restrict__ outp)
{
    __shared__ float r0[4], r1[4];
    const int b = blockIdx.x, d = threadIdx.x;
    float m = -INFINITY;
    for (int s = 0; s < Ss; ++s) {
        const size_t i = ((size_t)b * Ss + s) * Dd + d;
        m = fmaxf(m, aligned[i] + noise[i] - pred[i]);
    }
    pool_reduce_write(m, Wout, bout, outp, b, r0, r1);
}

// ---------------- host ----------------
extern "C" void kernel_launch(void* const* d_in, const int* in_sizes, int n_in,
                              void* d_out, int out_size, void* d_ws, size_t ws_size,
                              hipStream_t stream)
{
    const int*   seqs  = (const int*)d_in[0];
    const int*   tdiff = (const int*)d_in[5];
    const float* noise = (const float*)d_in[6];
    const float* emb   = (const float*)d_in[7];
    const float* Wih   = (const float*)d_in[8];
    const float* Whh   = (const float*)d_in[9];
    const float* bih   = (const float*)d_in[10];
    const float* bhh   = (const float*)d_in[11];
    const float* Whk   = (const float*)d_in[12];
    const float* bhk   = (const float*)d_in[13];
    const float* W1    = (const float*)d_in[14];
    const float* b1    = (const float*)d_in[15];
    const float* W2    = (const float*)d_in[16];
    const float* b2    = (const float*)d_in[17];
    const float* Wdiff = (const float*)d_in[18];
    const float* bdiff = (const float*)d_in[19];
    const float* temb  = (const float*)d_in[20];
    const float* Wout  = (const float*)d_in[21];
    const float* bout  = (const float*)d_in[22];

    float* outp = (float*)d_out;
    char*  wsb  = (char*)d_ws;

    bf16*  gatesb  = (bf16*) (wsb + OFFB_GATES);
    bf16*  embb    = (bf16*) (wsb + OFFB_EMBB);
    float* aligned = (float*)(wsb + OFFB_ALIGNED);
    bf16*  catb    = (bf16*) (wsb + OFFB_CAT);
    bf16*  tmpb    = (bf16*) (wsb + OFFB_TMPB);
    float* H1      = (float*)(wsb + OFFB_H1);
    float* attnw   = (float*)(wsb + OFFB_ATTNW);
    float* x       = (float*)(wsb + OFFB_X);
    bf16*  xb      = (bf16*) (wsb + OFFB_XB);
    bf16*  rnnb    = (bf16*) (wsb + OFFB_RNNB);
    float* wbuf    = (float*)(wsb + OFFB_W);
    bf16*  Wihb    = (bf16*) (wsb + OFFB_WIHB);
    bf16*  Whhb    = (bf16*) (wsb + OFFB_WHHB);
    bf16*  Whkb    = (bf16*) (wsb + OFFB_WHKB);
    bf16*  W1b     = (bf16*) (wsb + OFFB_W1B);
    bf16*  WdTb    = (bf16*) (wsb + OFFB_WDTB);
    float* salpha  = (float*)(wsb + OFFB_SALPHA);
    float* sbeta   = (float*)(wsb + OFFB_SBETA);

    float* pred_out  = outp + 1024;                        // (B,S,D)
    float* noise_out = outp + 1024 + (size_t)Bb * Ss * Dd; // (B,S,D)

    alpha_kernel<<<1, 256, 0, stream>>>(tdiff, salpha, sbeta);

    cvt_weights_kernel<<<608, 256, 0, stream>>>(Wih, Whh, Whk, W1,
                                                Wihb, Whhb, Whkb, W1b);
    transpose_cvt_kernel<<<dim3(8, 8), 256, 0, stream>>>(Wdiff, WdTb, 256, 256);
    cvt_emb_kernel<<<5001, 256, 0, stream>>>(emb, embb, 20001 * 64);

    // x = emb[seqs].sum(axis=2)  (fp32 + bf16), bf16 gather
    embed_kernel<<<Bb * Ss, 128, 0, stream>>>(seqs, (const unsigned*)embb, x, xb);

    // pool_x head (only needs x)
    pool_x_kernel<<<Bb, 256, 0, stream>>>(x, Wout, bout, outp);

    // gates_pre = x @ Wih^T + bih + bhh : (12800 x 1024), K=256, bf16 out
    mfma_gemm<128, 128, 0, 1><<<dim3(100, 8), 256, 0, stream>>>(
        xb, 256, Wihb, 256, bih, bhh, gatesb, 1024, 256);

    // LSTM recurrence: one launch, 16 independent blocks, no global sync
    lstm_rec<<<16, 512, 0, stream>>>(Whhb, gatesb, rnnb);

    // w = rnn @ Whk^T + bhk : (12800 x 256), K=256
    mfma_gemm<128, 128, 0, 0><<<dim3(100, 2), 256, 0, stream>>>(
        rnnb, 256, Whkb, 256, bhk, nullptr, wbuf, 256, 256);

    // attention MLP
    cat_build_kernel<<<Bb * (Ss - 1), 256, 0, stream>>>(x, wbuf, catb);
    mfma_gemm<128, 64, 1, 0><<<dim3(98, 1), 256, 0, stream>>>(
        catb, 512, W1b, 512, b1, nullptr, H1, 64, 512);
    attn2_kernel<<<(Bb * (Ss - 1)) / 4, 256, 0, stream>>>(H1, W2, b2, attnw);
    attn_apply_kernel<<<Bb * Ss, 256, 0, stream>>>(x, wbuf, attnw, aligned);

    // diffusion elementwise (+ noise passthrough fused)
    diff_kernel<<<Bb * Ss, 256, 0, stream>>>(aligned, noise, temb, tdiff,
                                             salpha, sbeta, tmpb, noise_out);

    // predicted_noise = tmp @ Wdiff + bdiff -> d_out
    mfma_gemm<128, 128, 0, 0><<<dim3(100, 2), 256, 0, stream>>>(
        tmpb, 256, WdTb, 256, bdiff, nullptr, pred_out, 256, 256);

    // gen_pool head: max_s(aligned + noise - pred) @ Wout^T + bout
    gen_pool_kernel<<<Bb, 256, 0, stream>>>(aligned, noise, pred_out, Wout, bout, outp + 512);
}

// Round 6
// 724.125 us; speedup vs baseline: 1.5598x; 1.5598x over previous
//
#include <hip/hip_runtime.h>
#include <cmath>

// Problem constants
#define Bb 256
#define Ss 50
#define Cc 40
#define Dd 256
#define Vv 20000

typedef __bf16 bf16;
typedef __bf16 bf16x8 __attribute__((ext_vector_type(8)));
typedef float f32x4 __attribute__((ext_vector_type(4)));

#define GL2LDS(g, l) __builtin_amdgcn_global_load_lds( \
    (__attribute__((address_space(1))) void*)(g), \
    (__attribute__((address_space(3))) void*)(l), 16, 0, 0)

// ---------------- ws layout (BYTE offsets) ----------------
// gates bf16 (12800x1024, PERMUTED cols) @0 (26MB); embb @0 dead after embed;
// post-recurrence the region is reused by aligned/cat/tmp/H1/attnw.
#define OFFB_GATES    0ull
#define OFFB_EMBB     0ull
#define OFFB_ALIGNED  0ull
#define OFFB_CAT      13107200ull
#define OFFB_TMPB     25952256ull
#define OFFB_H1       32505856ull
#define OFFB_ATTNW    35717120ull
#define OFFB_X        52428800ull
#define OFFB_XB       65536000ull
#define OFFB_RNNB     72089600ull
#define OFFB_W        78643200ull
#define OFFB_WIHB     92012544ull
#define OFFB_WHHB     92536832ull
#define OFFB_WHKB     93061120ull
#define OFFB_W1B      93192192ull
#define OFFB_WDTB     93257728ull
#define OFFB_SALPHA   93388800ull
#define OFFB_SBETA    93389824ull
#define OFFB_PBIAS    93390848ull   // fp32[1024] permuted bih+bhh
#define OFFB_WHHF     93394944ull   // bf16 fragment-major Whh (512KB)

__device__ __forceinline__ float fsig(float x) {
    return __fdividef(1.f, 1.f + __expf(-x));
}
__device__ __forceinline__ float ftanh(float x) {
    return 2.f * fsig(2.f * x) - 1.f;
}

// ---------------- bf16 MFMA GEMM ----------------
template<int BM, int BN, int ACT, int OBF>
__global__ __launch_bounds__(256) void mfma_gemm(
    const bf16* __restrict__ A, int lda,
    const bf16* __restrict__ B, int ldb,
    const float* __restrict__ bias1, const float* __restrict__ bias2,
    void* __restrict__ Cv, int ldc, int K)
{
    constexpr int BK = 32;
    constexpr int NF = BN / 32;
    __shared__ bf16 As[BM * BK];
    __shared__ bf16 Bs[BN * BK];
    const int tid  = threadIdx.x;
    const int wave = tid >> 6;
    const int lane = tid & 63;
    const int m0 = blockIdx.x * BM;
    const int n0 = blockIdx.y * BN;
    const int wm = (wave >> 1) * 64;
    const int wn = (wave & 1) * (BN / 2);

    f32x4 acc[4][NF];
#pragma unroll
    for (int i = 0; i < 4; ++i)
#pragma unroll
        for (int j = 0; j < NF; ++j) acc[i][j] = (f32x4){0.f, 0.f, 0.f, 0.f};

    const int ar = tid >> 2;
    const int ac = tid & 3;
    const int sw = ac ^ (ar & 3);
    const int lr = lane & 15;
    const int q  = lane >> 4;

    for (int k0 = 0; k0 < K; k0 += BK) {
        __syncthreads();
#pragma unroll
        for (int it = 0; it < BM / 64; ++it) {
            const bf16* gp = A + (size_t)(m0 + it * 64 + ar) * lda + k0 + sw * 8;
            GL2LDS(gp, As + it * 2048 + wave * 512);
        }
#pragma unroll
        for (int it = 0; it < BN / 64; ++it) {
            const bf16* gp = B + (size_t)(n0 + it * 64 + ar) * ldb + k0 + sw * 8;
            GL2LDS(gp, Bs + it * 2048 + wave * 512);
        }
        __syncthreads();

        bf16x8 af[4], bfv[NF];
#pragma unroll
        for (int fm = 0; fm < 4; ++fm) {
            int m = wm + fm * 16 + lr;
            af[fm] = *(const bf16x8*)(As + m * 32 + ((q ^ (m & 3)) * 8));
        }
#pragma unroll
        for (int fn = 0; fn < NF; ++fn) {
            int n = wn + fn * 16 + lr;
            bfv[fn] = *(const bf16x8*)(Bs + n * 32 + ((q ^ (n & 3)) * 8));
        }
#pragma unroll
        for (int fm = 0; fm < 4; ++fm)
#pragma unroll
            for (int fn = 0; fn < NF; ++fn)
                acc[fm][fn] = __builtin_amdgcn_mfma_f32_16x16x32_bf16(
                    af[fm], bfv[fn], acc[fm][fn], 0, 0, 0);
    }

    const int rbase = q * 4;
#pragma unroll
    for (int fn = 0; fn < NF; ++fn) {
        const int col = n0 + wn + fn * 16 + lr;
        float bb = 0.f;
        if (bias1) bb += bias1[col];
        if (bias2) bb += bias2[col];
#pragma unroll
        for (int fm = 0; fm < 4; ++fm) {
            f32x4 v = acc[fm][fn];
#pragma unroll
            for (int r = 0; r < 4; ++r) {
                const int row = m0 + wm + fm * 16 + rbase + r;
                float val = v[r] + bb;
                if (ACT == 1) val = tanhf(val);
                if (OBF)
                    ((bf16*)Cv)[(size_t)row * ldc + col] = (bf16)val;
                else
                    ((float*)Cv)[(size_t)row * ldc + col] = val;
            }
        }
    }
}

// ---------------- LSTM recurrence (R6 rework) ----------------
// 16 blocks x 512 threads (8 waves), zero cross-block comm. Wave w owns
// hidden dims w*32..+31 for all 4 gates (lane-local i/f/g/o combine).
// Whh in fragment-major layout: unit (w,g,j,kc) is a contiguous 1KB block,
// loaded at base+lane*16B (perfect coalescing). Gate0's 16 units pinned in
// registers (loaded once); gates1-3 streamed per step, double-buffered at
// tile granularity (unrolled alternation, NO buffer copies — R4's copies
// forced per-kc vmcnt drains; R5's JIT loads had only ~2 in flight @88 VGPR).
// Preacts: gates cols permuted at GEMM time so each thread's 8 values/row
// are one bf16x8 (4 vector loads/step vs 32 scalar).
__global__ __launch_bounds__(512, 2) void lstm_rec(
    const bf16* __restrict__ Whhf,    // fragment-major (512KB)
    const bf16* __restrict__ gatesb,  // (B*S x 1024) permuted cols, bf16
    bf16* __restrict__ rnnb)          // (B*S x 256) h outputs
{
    __shared__ bf16 hb[2][16][264];
    const int tid = threadIdx.x;
    const int w = tid >> 6, lane = tid & 63;
    const int lr = lane & 15, q = lane >> 4;
    const int bm = blockIdx.x;

    for (int i = tid; i < 16 * 264; i += 512)
        hb[0][i / 264][i % 264] = (bf16)0.f;

    // wave's fragment base: unit u = w*64 + (g*2+j)*8 + kc, elem = u*512+lane*8
    const bf16* wf = Whhf + ((size_t)w * 64) * 512 + lane * 8;

    // pinned gate-0 fragments (tiles 0,1)
    bf16x8 p0[8], p1[8];
#pragma unroll
    for (int kc = 0; kc < 8; ++kc) {
        p0[kc] = *(const bf16x8*)(wf + (0 + kc) * 512);
        p1[kc] = *(const bf16x8*)(wf + (8 + kc) * 512);
    }

    // preact base: row b = bm*16+q*4+r, permuted col base w*128+lr*8
    const bf16* gb[4];
#pragma unroll
    for (int r = 0; r < 4; ++r)
        gb[r] = gatesb + (size_t)((bm * 16 + q * 4 + r) * Ss) * 1024 + w * 128 + lr * 8;

    // h output base: row (b*Ss+t), col w*32 (+16 for j=1) + lr
    bf16* ob[4];
#pragma unroll
    for (int r = 0; r < 4; ++r)
        ob[r] = rnnb + (size_t)((bm * 16 + q * 4 + r) * Ss) * 256 + w * 32 + lr;

    float c0[4], c1[4];
#pragma unroll
    for (int r = 0; r < 4; ++r) { c0[r] = 0.f; c1[r] = 0.f; }

    __syncthreads();

    for (int t = 0; t < Ss; ++t) {
        const int p = t & 1;

        bf16x8 pgv[4];
#pragma unroll
        for (int r = 0; r < 4; ++r)
            pgv[r] = *(const bf16x8*)(gb[r] + t * 1024);

        f32x4 acc[4][2];
#pragma unroll
        for (int g = 0; g < 4; ++g) {
            acc[g][0] = (f32x4){0.f, 0.f, 0.f, 0.f};
            acc[g][1] = (f32x4){0.f, 0.f, 0.f, 0.f};
        }

        if (t > 0) {
            bf16x8 a[8];
#pragma unroll
            for (int kc = 0; kc < 8; ++kc)
                a[kc] = *(const bf16x8*)&hb[p][lr][kc * 32 + q * 8];

            bf16x8 bA[8], bB[8];
#pragma unroll
            for (int kc = 0; kc < 8; ++kc)                     // tile2 (g1,j0)
                bA[kc] = *(const bf16x8*)(wf + (16 + kc) * 512);
            // pinned gate-0 MFMAs cover tile2's load latency
#pragma unroll
            for (int kc = 0; kc < 8; ++kc) {
                acc[0][0] = __builtin_amdgcn_mfma_f32_16x16x32_bf16(a[kc], p0[kc], acc[0][0], 0, 0, 0);
                acc[0][1] = __builtin_amdgcn_mfma_f32_16x16x32_bf16(a[kc], p1[kc], acc[0][1], 0, 0, 0);
            }
#define LOADT(buf, ti) \
            _Pragma("unroll") for (int kc = 0; kc < 8; ++kc) \
                buf[kc] = *(const bf16x8*)(wf + ((ti) * 8 + kc) * 512);
#define MFMAT(buf, g, j) \
            _Pragma("unroll") for (int kc = 0; kc < 8; ++kc) \
                acc[g][j] = __builtin_amdgcn_mfma_f32_16x16x32_bf16(a[kc], buf[kc], acc[g][j], 0, 0, 0);
            LOADT(bB, 3)  MFMAT(bA, 1, 0)
            LOADT(bA, 4)  MFMAT(bB, 1, 1)
            LOADT(bB, 5)  MFMAT(bA, 2, 0)
            LOADT(bA, 6)  MFMAT(bB, 2, 1)
            LOADT(bB, 7)  MFMAT(bA, 3, 0)
                          MFMAT(bB, 3, 1)
#undef LOADT
#undef MFMAT
        }

#pragma unroll
        for (int r = 0; r < 4; ++r) {
            {   // j = 0: preact elems {0,2,4,6}
                float gi = acc[0][0][r] + (float)pgv[r][0];
                float gf = acc[1][0][r] + (float)pgv[r][2];
                float gg = acc[2][0][r] + (float)pgv[r][4];
                float go = acc[3][0][r] + (float)pgv[r][6];
                float ii = fsig(gi), ff = fsig(gf), g2 = ftanh(gg), oo = fsig(go);
                c0[r] = ff * c0[r] + ii * g2;
                bf16 hv = (bf16)(oo * ftanh(c0[r]));
                hb[p ^ 1][q * 4 + r][w * 32 + lr] = hv;
                ob[r][(size_t)t * 256] = hv;
            }
            {   // j = 1: preact elems {1,3,5,7}
                float gi = acc[0][1][r] + (float)pgv[r][1];
                float gf = acc[1][1][r] + (float)pgv[r][3];
                float gg = acc[2][1][r] + (float)pgv[r][5];
                float go = acc[3][1][r] + (float)pgv[r][7];
                float ii = fsig(gi), ff = fsig(gf), g2 = ftanh(gg), oo = fsig(go);
                c1[r] = ff * c1[r] + ii * g2;
                bf16 hv = (bf16)(oo * ftanh(c1[r]));
                hb[p ^ 1][q * 4 + r][w * 32 + 16 + lr] = hv;
                ob[r][(size_t)t * 256 + 16] = hv;
            }
        }
        __syncthreads();
    }
}

// ---------------- Whh -> fragment-major repack ----------------
__global__ __launch_bounds__(256) void whhf_repack_kernel(
    const bf16* __restrict__ Whhb, bf16* __restrict__ Whhf)
{
    int gid = blockIdx.x * 256 + threadIdx.x;   // 32768 total
    int lane = gid & 63, u = gid >> 6;
    int kc = u & 7, j = (u >> 3) & 1, g = (u >> 4) & 3, w = u >> 6;
    int lr = lane & 15, q = lane >> 4;
    int row = g * 256 + w * 32 + j * 16 + lr;
    int k   = kc * 32 + q * 8;
    *(bf16x8*)(Whhf + (size_t)gid * 8) = *(const bf16x8*)(Whhb + row * 256 + k);
}

// ---------------- weight converts (one launch, grid 609) ----------------
// Wih rows are PERMUTED so gates-GEMM output cols group each lstm thread's
// preacts contiguously: R' = w*128 + lr*8 + g*2 + j  <-  R = g*256+w*32+j*16+lr.
// Block 608 builds the matching permuted bias (bih+bhh).
__global__ __launch_bounds__(256) void cvt_weights_kernel(
    const float* __restrict__ Wih, const float* __restrict__ Whh,
    const float* __restrict__ Whk, const float* __restrict__ W1,
    const float* __restrict__ bih, const float* __restrict__ bhh,
    bf16* __restrict__ Wihb, bf16* __restrict__ Whhb,
    bf16* __restrict__ Whkb, bf16* __restrict__ W1b,
    float* __restrict__ pbias)
{
    if (blockIdx.x == 608) {
#pragma unroll
        for (int k = 0; k < 4; ++k) {
            int idx = threadIdx.x + 256 * k;   // R'
            int w = idx >> 7, lr = (idx >> 3) & 15, g = (idx >> 1) & 3, j = idx & 1;
            int R = g * 256 + w * 32 + j * 16 + lr;
            pbias[idx] = bih[R] + bhh[R];
        }
        return;
    }
    int i = blockIdx.x * 256 + threadIdx.x;   // float4 index
    if (i < 65536) {
        int R = i >> 6, c4 = i & 63;
        int g = R >> 8, w = (R >> 5) & 7, j = (R >> 4) & 1, lr = R & 15;
        int Rp = w * 128 + lr * 8 + g * 2 + j;
        float4 v = *((const float4*)Wih + i);
        bf16* o = Wihb + Rp * 256 + c4 * 4;
        o[0] = (bf16)v.x; o[1] = (bf16)v.y; o[2] = (bf16)v.z; o[3] = (bf16)v.w;
        return;
    }
    const float* src; bf16* dst; int base;
    if (i < 131072)      { src = Whh; dst = Whhb; base = 65536; }
    else if (i < 147456) { src = Whk; dst = Whkb; base = 131072; }
    else                 { src = W1;  dst = W1b;  base = 147456; }
    int j = i - base;
    float4 v = *((const float4*)src + j);
    bf16* o = dst + j * 4;
    o[0] = (bf16)v.x; o[1] = (bf16)v.y; o[2] = (bf16)v.z; o[3] = (bf16)v.w;
}

__global__ __launch_bounds__(256) void cvt_emb_kernel(
    const float* __restrict__ src, bf16* __restrict__ dst, int n4)
{
    int i = blockIdx.x * 256 + threadIdx.x;
    if (i >= n4) return;
    float4 v = *((const float4*)src + i);
    bf16* o = dst + i * 4;
    o[0] = (bf16)v.x; o[1] = (bf16)v.y; o[2] = (bf16)v.z; o[3] = (bf16)v.w;
}

__global__ __launch_bounds__(256) void transpose_cvt_kernel(
    const float* __restrict__ in, bf16* __restrict__ out, int R, int C)
{
    __shared__ float t[32][33];
    const int c0 = blockIdx.x * 32, r0 = blockIdx.y * 32;
    const int tx = threadIdx.x & 31, ty = threadIdx.x >> 5;
    for (int i = ty; i < 32; i += 8)
        t[i][tx] = in[(size_t)(r0 + i) * C + c0 + tx];
    __syncthreads();
    for (int i = ty; i < 32; i += 8)
        out[(size_t)(c0 + i) * R + r0 + tx] = (bf16)t[tx][i];
}

// ---------------- per-batch diffusion scale factors ----------------
__global__ void alpha_kernel(const int* __restrict__ tdiff,
                             float* __restrict__ salpha, float* __restrict__ sbeta)
{
    const int b = threadIdx.x;
    const int t = tdiff[b];
    const float step = (0.02f - 1e-4f) / 999.f;
    float prod = 1.f;
    for (int j = 0; j <= t; ++j) prod *= (1.f - (1e-4f + j * step));
    salpha[b] = sqrtf(prod);
    sbeta[b]  = sqrtf(fmaxf(1.f - prod, 0.f));
}

// ---------------- embedding gather-sum from bf16 table ----------------
__global__ __launch_bounds__(128) void embed_kernel(
    const int* __restrict__ seqs, const unsigned* __restrict__ emb2,
    float* __restrict__ x, bf16* __restrict__ xb)
{
    __shared__ int idx[Cc];
    const int bs = blockIdx.x;
    const int tid = threadIdx.x;
    if (tid < Cc) idx[tid] = seqs[(size_t)bs * Cc + tid];
    __syncthreads();
    float s0 = 0.f, s1 = 0.f;
#pragma unroll 8
    for (int c = 0; c < Cc; ++c) {
        unsigned u = emb2[(size_t)idx[c] * 128 + tid];
        union { unsigned ui; float f; } lo, hi;
        lo.ui = u << 16;
        hi.ui = u & 0xffff0000u;
        s0 += lo.f;
        s1 += hi.f;
    }
    ((float2*)x)[(size_t)bs * 128 + tid] = make_float2(s0, s1);
    union { bf16 h[2]; unsigned u; } pk;
    pk.h[0] = (bf16)s0; pk.h[1] = (bf16)s1;
    ((unsigned*)xb)[(size_t)bs * 128 + tid] = pk.u;
}

// ---------------- attention: cat build (bf16), logits, apply ----------------
__global__ __launch_bounds__(256) void cat_build_kernel(
    const float* __restrict__ x, const float* __restrict__ w, bf16* __restrict__ cat)
{
    const int r = blockIdx.x;             // b*49+t
    const int b = r / (Ss - 1), t = r % (Ss - 1);
    const int d = threadIdx.x;
    cat[(size_t)r * 512 + d]       = (bf16)x[((size_t)b * Ss) * Dd + d];
    cat[(size_t)r * 512 + 256 + d] = (bf16)w[((size_t)b * Ss + t) * Dd + d];
}

__global__ __launch_bounds__(256) void attn2_kernel(
    const float* __restrict__ H1, const float* __restrict__ W2,
    const float* __restrict__ b2, float* __restrict__ attnw)
{
    const int r = blockIdx.x * 4 + (threadIdx.x >> 6);
    const int j = threadIdx.x & 63;
    float h = H1[(size_t)r * 64 + j];
    float v0 = h * W2[j];
    float v1 = h * W2[64 + j];
#pragma unroll
    for (int off = 32; off; off >>= 1) { v0 += __shfl_down(v0, off); v1 += __shfl_down(v1, off); }
    if (j == 0) {
        float z0 = v0 + b2[0], z1 = v1 + b2[1];
        float m = fmaxf(z0, z1);
        float e0 = expf(z0 - m), e1 = expf(z1 - m);
        float inv = 1.f / (e0 + e1);
        attnw[(size_t)r * 2 + 0] = e0 * inv;
        attnw[(size_t)r * 2 + 1] = e1 * inv;
    }
}

__global__ __launch_bounds__(256) void attn_apply_kernel(
    const float* __restrict__ x, const float* __restrict__ w,
    const float* __restrict__ attnw, float* __restrict__ aligned)
{
    const int bs = blockIdx.x;
    const int b = bs / Ss, s = bs % Ss;
    const int d = threadIdx.x;
    const float ek = x[((size_t)b * Ss) * Dd + d];
    float v;
    if (s == 0) {
        v = ek;
    } else {
        const int r = b * (Ss - 1) + (s - 1);
        const float a0 = attnw[(size_t)r * 2], a1 = attnw[(size_t)r * 2 + 1];
        v = ek * a0 + w[((size_t)b * Ss + s - 1) * Dd + d] * a1;
    }
    aligned[(size_t)bs * Dd + d] = v;
}

// ---------------- diffusion elementwise + noise passthrough ----------------
__global__ __launch_bounds__(256) void diff_kernel(
    const float* __restrict__ aligned, const float* __restrict__ noise,
    const float* __restrict__ temb, const int* __restrict__ tdiff,
    const float* __restrict__ salpha, const float* __restrict__ sbeta,
    bf16* __restrict__ tmpb, float* __restrict__ noise_out)
{
    const int bs = blockIdx.x;
    const int b = bs / Ss;
    const int d = threadIdx.x;
    const size_t i = (size_t)bs * Dd + d;
    const int t = tdiff[b];
    const float nz = noise[i];
    tmpb[i] = (bf16)(aligned[i] * salpha[b] + nz * sbeta[b] + temb[(size_t)t * Dd + d]);
    noise_out[i] = nz;
}

// ---------------- pooled 2-class heads ----------------
__device__ inline void pool_reduce_write(float m, const float* __restrict__ Wout,
                                         const float* __restrict__ bout,
                                         float* __restrict__ outp, int b,
                                         float* r0, float* r1)
{
    float v0 = m * Wout[threadIdx.x];
    float v1 = m * Wout[Dd + threadIdx.x];
#pragma unroll
    for (int off = 32; off; off >>= 1) { v0 += __shfl_down(v0, off); v1 += __shfl_down(v1, off); }
    const int lane = threadIdx.x & 63, wv = threadIdx.x >> 6;
    if (lane == 0) { r0[wv] = v0; r1[wv] = v1; }
    __syncthreads();
    if (threadIdx.x == 0) {
        outp[b * 2 + 0] = r0[0] + r0[1] + r0[2] + r0[3] + bout[0];
        outp[b * 2 + 1] = r1[0] + r1[1] + r1[2] + r1[3] + bout[1];
    }
}

__global__ __launch_bounds__(256) void pool_x_kernel(
    const float* __restrict__ x, const float* __restrict__ Wout,
    const float* __restrict__ bout, float* __restrict__ outp)
{
    __shared__ float r0[4], r1[4];
    const int b = blockIdx.x, d = threadIdx.x;
    float m = -INFINITY;
    for (int s = 0; s < Ss; ++s) m = fmaxf(m, x[((size_t)b * Ss + s) * Dd + d]);
    pool_reduce_write(m, Wout, bout, outp, b, r0, r1);
}

__global__ __launch_bounds__(256) void gen_pool_kernel(
    const float* __restrict__ aligned, const float* __restrict__ noise,
    const float* __restrict__ pred, const float* __restrict__ Wout,
    const float* __restrict__ bout, float* __restrict__ outp)
{
    __shared__ float r0[4], r1[4];
    const int b = blockIdx.x, d = threadIdx.x;
    float m = -INFINITY;
    for (int s = 0; s < Ss; ++s) {
        const size_t i = ((size_t)b * Ss + s) * Dd + d;
        m = fmaxf(m, aligned[i] + noise[i] - pred[i]);
    }
    pool_reduce_write(m, Wout, bout, outp, b, r0, r1);
}

// ---------------- host ----------------
extern "C" void kernel_launch(void* const* d_in, const int* in_sizes, int n_in,
                              void* d_out, int out_size, void* d_ws, size_t ws_size,
                              hipStream_t stream)
{
    const int*   seqs  = (const int*)d_in[0];
    const int*   tdiff = (const int*)d_in[5];
    const float* noise = (const float*)d_in[6];
    const float* emb   = (const float*)d_in[7];
    const float* Wih   = (const float*)d_in[8];
    const float* Whh   = (const float*)d_in[9];
    const float* bih   = (const float*)d_in[10];
    const float* bhh   = (const float*)d_in[11];
    const float* Whk   = (const float*)d_in[12];
    const float* bhk   = (const float*)d_in[13];
    const float* W1    = (const float*)d_in[14];
    const float* b1    = (const float*)d_in[15];
    const float* W2    = (const float*)d_in[16];
    const float* b2    = (const float*)d_in[17];
    const float* Wdiff = (const float*)d_in[18];
    const float* bdiff = (const float*)d_in[19];
    const float* temb  = (const float*)d_in[20];
    const float* Wout  = (const float*)d_in[21];
    const float* bout  = (const float*)d_in[22];

    float* outp = (float*)d_out;
    char*  wsb  = (char*)d_ws;

    bf16*  gatesb  = (bf16*) (wsb + OFFB_GATES);
    bf16*  embb    = (bf16*) (wsb + OFFB_EMBB);
    float* aligned = (float*)(wsb + OFFB_ALIGNED);
    bf16*  catb    = (bf16*) (wsb + OFFB_CAT);
    bf16*  tmpb    = (bf16*) (wsb + OFFB_TMPB);
    float* H1      = (float*)(wsb + OFFB_H1);
    float* attnw   = (float*)(wsb + OFFB_ATTNW);
    float* x       = (float*)(wsb + OFFB_X);
    bf16*  xb      = (bf16*) (wsb + OFFB_XB);
    bf16*  rnnb    = (bf16*) (wsb + OFFB_RNNB);
    float* wbuf    = (float*)(wsb + OFFB_W);
    bf16*  Wihb    = (bf16*) (wsb + OFFB_WIHB);
    bf16*  Whhb    = (bf16*) (wsb + OFFB_WHHB);
    bf16*  Whkb    = (bf16*) (wsb + OFFB_WHKB);
    bf16*  W1b     = (bf16*) (wsb + OFFB_W1B);
    bf16*  WdTb    = (bf16*) (wsb + OFFB_WDTB);
    float* salpha  = (float*)(wsb + OFFB_SALPHA);
    float* sbeta   = (float*)(wsb + OFFB_SBETA);
    float* pbias   = (float*)(wsb + OFFB_PBIAS);
    bf16*  Whhf    = (bf16*) (wsb + OFFB_WHHF);

    float* pred_out  = outp + 1024;                        // (B,S,D)
    float* noise_out = outp + 1024 + (size_t)Bb * Ss * Dd; // (B,S,D)

    alpha_kernel<<<1, 256, 0, stream>>>(tdiff, salpha, sbeta);

    cvt_weights_kernel<<<609, 256, 0, stream>>>(Wih, Whh, Whk, W1, bih, bhh,
                                                Wihb, Whhb, Whkb, W1b, pbias);
    whhf_repack_kernel<<<128, 256, 0, stream>>>(Whhb, Whhf);
    transpose_cvt_kernel<<<dim3(8, 8), 256, 0, stream>>>(Wdiff, WdTb, 256, 256);
    cvt_emb_kernel<<<5001, 256, 0, stream>>>(emb, embb, 20001 * 64);

    // x = emb[seqs].sum(axis=2)  (fp32 + bf16), bf16 gather
    embed_kernel<<<Bb * Ss, 128, 0, stream>>>(seqs, (const unsigned*)embb, x, xb);

    // pool_x head (only needs x)
    pool_x_kernel<<<Bb, 256, 0, stream>>>(x, Wout, bout, outp);

    // gates_pre = x @ Wih^T + (bih+bhh), permuted cols, bf16 out
    mfma_gemm<128, 128, 0, 1><<<dim3(100, 8), 256, 0, stream>>>(
        xb, 256, Wihb, 256, pbias, nullptr, gatesb, 1024, 256);

    // LSTM recurrence: one launch, 16 independent blocks
    lstm_rec<<<16, 512, 0, stream>>>(Whhf, gatesb, rnnb);

    // w = rnn @ Whk^T + bhk : (12800 x 256), K=256
    mfma_gemm<128, 128, 0, 0><<<dim3(100, 2), 256, 0, stream>>>(
        rnnb, 256, Whkb, 256, bhk, nullptr, wbuf, 256, 256);

    // attention MLP
    cat_build_kernel<<<Bb * (Ss - 1), 256, 0, stream>>>(x, wbuf, catb);
    mfma_gemm<128, 64, 1, 0><<<dim3(98, 1), 256, 0, stream>>>(
        catb, 512, W1b, 512, b1, nullptr, H1, 64, 512);
    attn2_kernel<<<(Bb * (Ss - 1)) / 4, 256, 0, stream>>>(H1, W2, b2, attnw);
    attn_apply_kernel<<<Bb * Ss, 256, 0, stream>>>(x, wbuf, attnw, aligned);

    // diffusion elementwise (+ noise passthrough fused)
    diff_kernel<<<Bb * Ss, 256, 0, stream>>>(aligned, noise, temb, tdiff,
                                             salpha, sbeta, tmpb, noise_out);

    // predicted_noise = tmp @ Wdiff + bdiff -> d_out
    mfma_gemm<128, 128, 0, 0><<<dim3(100, 2), 256, 0, stream>>>(
        tmpb, 256, WdTb, 256, bdiff, nullptr, pred_out, 256, 256);

    // gen_pool head: max_s(aligned + noise - pred) @ Wout^T + bout
    gen_pool_kernel<<<Bb, 256, 0, stream>>>(aligned, noise, pred_out, Wout, bout, outp + 512);
}

// Round 7
// 678.431 us; speedup vs baseline: 1.6649x; 1.0674x over previous
//
#include <hip/hip_runtime.h>
#include <cmath>

// Problem constants
#define Bb 256
#define Ss 50
#define Cc 40
#define Dd 256
#define Vv 20000

typedef __bf16 bf16;
typedef __bf16 bf16x8 __attribute__((ext_vector_type(8)));
typedef __bf16 bf16x4 __attribute__((ext_vector_type(4)));
typedef float f32x4 __attribute__((ext_vector_type(4)));

#define GL2LDS(g, l) __builtin_amdgcn_global_load_lds( \
    (__attribute__((address_space(1))) void*)(g), \
    (__attribute__((address_space(3))) void*)(l), 16, 0, 0)

// ---------------- ws layout (BYTE offsets) ----------------
#define OFFB_GATES    0ull
#define OFFB_EMBB     0ull
#define OFFB_ALIGNED  0ull
#define OFFB_CAT      13107200ull
#define OFFB_TMPB     25952256ull
#define OFFB_H1       32505856ull
#define OFFB_ATTNW    35717120ull
#define OFFB_X        52428800ull
#define OFFB_XB       65536000ull
#define OFFB_RNNB     72089600ull
#define OFFB_W        78643200ull
#define OFFB_WIHB     92012544ull
#define OFFB_WHHB     92536832ull
#define OFFB_WHKB     93061120ull
#define OFFB_W1B      93192192ull
#define OFFB_WDTB     93257728ull
#define OFFB_SALPHA   93388800ull
#define OFFB_SBETA    93389824ull
#define OFFB_PBIAS    93390848ull   // fp32[1024] permuted bih+bhh
#define OFFB_WHHF     93394944ull   // bf16 fragment-major Whh (512KB)

__device__ __forceinline__ float fsig(float x) {
    return __fdividef(1.f, 1.f + __expf(-x));
}
__device__ __forceinline__ float ftanh(float x) {
    return 2.f * fsig(2.f * x) - 1.f;
}

// ---------------- bf16 MFMA GEMM ----------------
template<int BM, int BN, int ACT, int OBF>
__global__ __launch_bounds__(256) void mfma_gemm(
    const bf16* __restrict__ A, int lda,
    const bf16* __restrict__ B, int ldb,
    const float* __restrict__ bias1, const float* __restrict__ bias2,
    void* __restrict__ Cv, int ldc, int K)
{
    constexpr int BK = 32;
    constexpr int NF = BN / 32;
    __shared__ bf16 As[BM * BK];
    __shared__ bf16 Bs[BN * BK];
    const int tid  = threadIdx.x;
    const int wave = tid >> 6;
    const int lane = tid & 63;
    const int m0 = blockIdx.x * BM;
    const int n0 = blockIdx.y * BN;
    const int wm = (wave >> 1) * 64;
    const int wn = (wave & 1) * (BN / 2);

    f32x4 acc[4][NF];
#pragma unroll
    for (int i = 0; i < 4; ++i)
#pragma unroll
        for (int j = 0; j < NF; ++j) acc[i][j] = (f32x4){0.f, 0.f, 0.f, 0.f};

    const int ar = tid >> 2;
    const int ac = tid & 3;
    const int sw = ac ^ (ar & 3);
    const int lr = lane & 15;
    const int q  = lane >> 4;

    for (int k0 = 0; k0 < K; k0 += BK) {
        __syncthreads();
#pragma unroll
        for (int it = 0; it < BM / 64; ++it) {
            const bf16* gp = A + (size_t)(m0 + it * 64 + ar) * lda + k0 + sw * 8;
            GL2LDS(gp, As + it * 2048 + wave * 512);
        }
#pragma unroll
        for (int it = 0; it < BN / 64; ++it) {
            const bf16* gp = B + (size_t)(n0 + it * 64 + ar) * ldb + k0 + sw * 8;
            GL2LDS(gp, Bs + it * 2048 + wave * 512);
        }
        __syncthreads();

        bf16x8 af[4], bfv[NF];
#pragma unroll
        for (int fm = 0; fm < 4; ++fm) {
            int m = wm + fm * 16 + lr;
            af[fm] = *(const bf16x8*)(As + m * 32 + ((q ^ (m & 3)) * 8));
        }
#pragma unroll
        for (int fn = 0; fn < NF; ++fn) {
            int n = wn + fn * 16 + lr;
            bfv[fn] = *(const bf16x8*)(Bs + n * 32 + ((q ^ (n & 3)) * 8));
        }
#pragma unroll
        for (int fm = 0; fm < 4; ++fm)
#pragma unroll
            for (int fn = 0; fn < NF; ++fn)
                acc[fm][fn] = __builtin_amdgcn_mfma_f32_16x16x32_bf16(
                    af[fm], bfv[fn], acc[fm][fn], 0, 0, 0);
    }

    const int rbase = q * 4;
#pragma unroll
    for (int fn = 0; fn < NF; ++fn) {
        const int col = n0 + wn + fn * 16 + lr;
        float bb = 0.f;
        if (bias1) bb += bias1[col];
        if (bias2) bb += bias2[col];
#pragma unroll
        for (int fm = 0; fm < 4; ++fm) {
            f32x4 v = acc[fm][fn];
#pragma unroll
            for (int r = 0; r < 4; ++r) {
                const int row = m0 + wm + fm * 16 + rbase + r;
                float val = v[r] + bb;
                if (ACT == 1) val = tanhf(val);
                if (OBF)
                    ((bf16*)Cv)[(size_t)row * ldc + col] = (bf16)val;
                else
                    ((float*)Cv)[(size_t)row * ldc + col] = val;
            }
        }
    }
}

// ---------------- LSTM recurrence (R7: 16 waves/block) ----------------
// 16 blocks x 1024 threads (16 waves = 4 waves/SIMD — double R6's latency
// hiding). Wave v owns hidden dims v*16..+15 for ALL 4 gates: 4 MFMA tiles
// per wave (vs 8), lane-local i/f/g/o combine, 4 h-units/lane. Whh stream
// 32KB/wave/step in fragment-major 1KB units (coalesced); two-tile double
// buffer, no copies. Preacts: permuted cols R'=v*64+lr*4+g so each lane's
// 4 gates/row are one 8B load. c in regs; h ping-pongs via LDS.
__global__ __launch_bounds__(1024, 4) void lstm_rec(
    const bf16* __restrict__ Whhf,    // fragment-major (512KB)
    const bf16* __restrict__ gatesb,  // (B*S x 1024) permuted cols, bf16
    bf16* __restrict__ rnnb)          // (B*S x 256) h outputs
{
    __shared__ bf16 hb[2][16][264];
    const int tid = threadIdx.x;
    const int v = tid >> 6, lane = tid & 63;
    const int lr = lane & 15, q = lane >> 4;
    const int bm = blockIdx.x;

    for (int i = tid; i < 16 * 264; i += 1024)
        hb[0][i / 264][i % 264] = (bf16)0.f;

    // wave fragment base: unit u = v*32 + g*8 + kc; elem = u*512 + lane*8
    const bf16* wf = Whhf + ((size_t)v * 32) * 512 + lane * 8;

    // preact base per r: row bm*16+q*4+r, permuted col v*64+lr*4
    const bf16* gb[4];
#pragma unroll
    for (int r = 0; r < 4; ++r)
        gb[r] = gatesb + (size_t)((bm * 16 + q * 4 + r) * Ss) * 1024 + v * 64 + lr * 4;

    // h output base per r: row (b*Ss+t), col v*16+lr
    bf16* ob[4];
#pragma unroll
    for (int r = 0; r < 4; ++r)
        ob[r] = rnnb + (size_t)((bm * 16 + q * 4 + r) * Ss) * 256 + v * 16 + lr;

    float c[4];
#pragma unroll
    for (int r = 0; r < 4; ++r) c[r] = 0.f;

    __syncthreads();

    for (int t = 0; t < Ss; ++t) {
        const int p = t & 1;

        // preact loads first (oldest in vmcnt queue -> done before gate math)
        bf16x4 pgv[4];
#pragma unroll
        for (int r = 0; r < 4; ++r)
            pgv[r] = *(const bf16x4*)(gb[r] + t * 1024);

        f32x4 acc[4];
#pragma unroll
        for (int g = 0; g < 4; ++g) acc[g] = (f32x4){0.f, 0.f, 0.f, 0.f};

        if (t > 0) {
            bf16x8 a[8];
#pragma unroll
            for (int kc = 0; kc < 8; ++kc)
                a[kc] = *(const bf16x8*)&hb[p][lr][kc * 32 + q * 8];

            bf16x8 bA[8], bB[8];
#define LOADT(buf, g) \
            _Pragma("unroll") for (int kc = 0; kc < 8; ++kc) \
                buf[kc] = *(const bf16x8*)(wf + ((g) * 8 + kc) * 512);
#define MFMAT(buf, g) \
            _Pragma("unroll") for (int kc = 0; kc < 8; ++kc) \
                acc[g] = __builtin_amdgcn_mfma_f32_16x16x32_bf16(a[kc], buf[kc], acc[g], 0, 0, 0);
            LOADT(bA, 0)
            LOADT(bB, 1)  MFMAT(bA, 0)
            LOADT(bA, 2)  MFMAT(bB, 1)
            LOADT(bB, 3)  MFMAT(bA, 2)
                          MFMAT(bB, 3)
#undef LOADT
#undef MFMAT
        }

        // gate math: lane-local; acc[g] reg r -> (m=q*4+r, d=v*16+lr)
#pragma unroll
        for (int r = 0; r < 4; ++r) {
            float gi = acc[0][r] + (float)pgv[r][0];
            float gf = acc[1][r] + (float)pgv[r][1];
            float gg = acc[2][r] + (float)pgv[r][2];
            float go = acc[3][r] + (float)pgv[r][3];
            float ii = fsig(gi), ff = fsig(gf), g2 = ftanh(gg), oo = fsig(go);
            c[r] = ff * c[r] + ii * g2;
            bf16 hv = (bf16)(oo * ftanh(c[r]));
            hb[p ^ 1][q * 4 + r][v * 16 + lr] = hv;
            ob[r][(size_t)t * 256] = hv;
        }
        __syncthreads();
    }
}

// ---------------- Whh -> fragment-major repack (16-wave unit order) ------
__global__ __launch_bounds__(256) void whhf_repack_kernel(
    const bf16* __restrict__ Whhb, bf16* __restrict__ Whhf)
{
    int gid = blockIdx.x * 256 + threadIdx.x;   // 32768 total
    int lane = gid & 63, u = gid >> 6;          // u = v*32 + g*8 + kc
    int kc = u & 7, g = (u >> 3) & 3, v = u >> 5;
    int lr = lane & 15, q = lane >> 4;
    int row = g * 256 + v * 16 + lr;
    int k   = kc * 32 + q * 8;
    *(bf16x8*)(Whhf + (size_t)gid * 8) = *(const bf16x8*)(Whhb + row * 256 + k);
}

// ---------------- weight converts (one launch, grid 609) ----------------
// Wih rows PERMUTED: R' = v*64 + lr*4 + g  <-  R = g*256 + v*16 + lr, so the
// gates-GEMM output groups each lstm lane's 4 gate preacts contiguously.
// Block 608 builds the matching permuted bias (bih+bhh).
__global__ __launch_bounds__(256) void cvt_weights_kernel(
    const float* __restrict__ Wih, const float* __restrict__ Whh,
    const float* __restrict__ Whk, const float* __restrict__ W1,
    const float* __restrict__ bih, const float* __restrict__ bhh,
    bf16* __restrict__ Wihb, bf16* __restrict__ Whhb,
    bf16* __restrict__ Whkb, bf16* __restrict__ W1b,
    float* __restrict__ pbias)
{
    if (blockIdx.x == 608) {
#pragma unroll
        for (int k = 0; k < 4; ++k) {
            int idx = threadIdx.x + 256 * k;   // R'
            int v = idx >> 6, lr = (idx >> 2) & 15, g = idx & 3;
            int R = g * 256 + v * 16 + lr;
            pbias[idx] = bih[R] + bhh[R];
        }
        return;
    }
    int i = blockIdx.x * 256 + threadIdx.x;   // float4 index
    if (i < 65536) {
        int R = i >> 6, c4 = i & 63;
        int g = R >> 8, v = (R >> 4) & 15, lr = R & 15;
        int Rp = v * 64 + lr * 4 + g;
        float4 vv = *((const float4*)Wih + i);
        bf16* o = Wihb + Rp * 256 + c4 * 4;
        o[0] = (bf16)vv.x; o[1] = (bf16)vv.y; o[2] = (bf16)vv.z; o[3] = (bf16)vv.w;
        return;
    }
    const float* src; bf16* dst; int base;
    if (i < 131072)      { src = Whh; dst = Whhb; base = 65536; }
    else if (i < 147456) { src = Whk; dst = Whkb; base = 131072; }
    else                 { src = W1;  dst = W1b;  base = 147456; }
    int j = i - base;
    float4 vv = *((const float4*)src + j);
    bf16* o = dst + j * 4;
    o[0] = (bf16)vv.x; o[1] = (bf16)vv.y; o[2] = (bf16)vv.z; o[3] = (bf16)vv.w;
}

__global__ __launch_bounds__(256) void cvt_emb_kernel(
    const float* __restrict__ src, bf16* __restrict__ dst, int n4)
{
    int i = blockIdx.x * 256 + threadIdx.x;
    if (i >= n4) return;
    float4 v = *((const float4*)src + i);
    bf16* o = dst + i * 4;
    o[0] = (bf16)v.x; o[1] = (bf16)v.y; o[2] = (bf16)v.z; o[3] = (bf16)v.w;
}

__global__ __launch_bounds__(256) void transpose_cvt_kernel(
    const float* __restrict__ in, bf16* __restrict__ out, int R, int C)
{
    __shared__ float t[32][33];
    const int c0 = blockIdx.x * 32, r0 = blockIdx.y * 32;
    const int tx = threadIdx.x & 31, ty = threadIdx.x >> 5;
    for (int i = ty; i < 32; i += 8)
        t[i][tx] = in[(size_t)(r0 + i) * C + c0 + tx];
    __syncthreads();
    for (int i = ty; i < 32; i += 8)
        out[(size_t)(c0 + i) * R + r0 + tx] = (bf16)t[tx][i];
}

// ---------------- per-batch diffusion scale factors ----------------
__global__ void alpha_kernel(const int* __restrict__ tdiff,
                             float* __restrict__ salpha, float* __restrict__ sbeta)
{
    const int b = threadIdx.x;
    const int t = tdiff[b];
    const float step = (0.02f - 1e-4f) / 999.f;
    float prod = 1.f;
    for (int j = 0; j <= t; ++j) prod *= (1.f - (1e-4f + j * step));
    salpha[b] = sqrtf(prod);
    sbeta[b]  = sqrtf(fmaxf(1.f - prod, 0.f));
}

// ---------------- embedding gather-sum from bf16 table ----------------
__global__ __launch_bounds__(128) void embed_kernel(
    const int* __restrict__ seqs, const unsigned* __restrict__ emb2,
    float* __restrict__ x, bf16* __restrict__ xb)
{
    __shared__ int idx[Cc];
    const int bs = blockIdx.x;
    const int tid = threadIdx.x;
    if (tid < Cc) idx[tid] = seqs[(size_t)bs * Cc + tid];
    __syncthreads();
    float s0 = 0.f, s1 = 0.f;
#pragma unroll 8
    for (int c = 0; c < Cc; ++c) {
        unsigned u = emb2[(size_t)idx[c] * 128 + tid];
        union { unsigned ui; float f; } lo, hi;
        lo.ui = u << 16;
        hi.ui = u & 0xffff0000u;
        s0 += lo.f;
        s1 += hi.f;
    }
    ((float2*)x)[(size_t)bs * 128 + tid] = make_float2(s0, s1);
    union { bf16 h[2]; unsigned u; } pk;
    pk.h[0] = (bf16)s0; pk.h[1] = (bf16)s1;
    ((unsigned*)xb)[(size_t)bs * 128 + tid] = pk.u;
}

// ---------------- attention: cat build (bf16), logits, apply ----------------
__global__ __launch_bounds__(256) void cat_build_kernel(
    const float* __restrict__ x, const float* __restrict__ w, bf16* __restrict__ cat)
{
    const int r = blockIdx.x;             // b*49+t
    const int b = r / (Ss - 1), t = r % (Ss - 1);
    const int d = threadIdx.x;
    cat[(size_t)r * 512 + d]       = (bf16)x[((size_t)b * Ss) * Dd + d];
    cat[(size_t)r * 512 + 256 + d] = (bf16)w[((size_t)b * Ss + t) * Dd + d];
}

__global__ __launch_bounds__(256) void attn2_kernel(
    const float* __restrict__ H1, const float* __restrict__ W2,
    const float* __restrict__ b2, float* __restrict__ attnw)
{
    const int r = blockIdx.x * 4 + (threadIdx.x >> 6);
    const int j = threadIdx.x & 63;
    float h = H1[(size_t)r * 64 + j];
    float v0 = h * W2[j];
    float v1 = h * W2[64 + j];
#pragma unroll
    for (int off = 32; off; off >>= 1) { v0 += __shfl_down(v0, off); v1 += __shfl_down(v1, off); }
    if (j == 0) {
        float z0 = v0 + b2[0], z1 = v1 + b2[1];
        float m = fmaxf(z0, z1);
        float e0 = expf(z0 - m), e1 = expf(z1 - m);
        float inv = 1.f / (e0 + e1);
        attnw[(size_t)r * 2 + 0] = e0 * inv;
        attnw[(size_t)r * 2 + 1] = e1 * inv;
    }
}

__global__ __launch_bounds__(256) void attn_apply_kernel(
    const float* __restrict__ x, const float* __restrict__ w,
    const float* __restrict__ attnw, float* __restrict__ aligned)
{
    const int bs = blockIdx.x;
    const int b = bs / Ss, s = bs % Ss;
    const int d = threadIdx.x;
    const float ek = x[((size_t)b * Ss) * Dd + d];
    float v;
    if (s == 0) {
        v = ek;
    } else {
        const int r = b * (Ss - 1) + (s - 1);
        const float a0 = attnw[(size_t)r * 2], a1 = attnw[(size_t)r * 2 + 1];
        v = ek * a0 + w[((size_t)b * Ss + s - 1) * Dd + d] * a1;
    }
    aligned[(size_t)bs * Dd + d] = v;
}

// ---------------- diffusion elementwise + noise passthrough ----------------
__global__ __launch_bounds__(256) void diff_kernel(
    const float* __restrict__ aligned, const float* __restrict__ noise,
    const float* __restrict__ temb, const int* __restrict__ tdiff,
    const float* __restrict__ salpha, const float* __restrict__ sbeta,
    bf16* __restrict__ tmpb, float* __restrict__ noise_out)
{
    const int bs = blockIdx.x;
    const int b = bs / Ss;
    const int d = threadIdx.x;
    const size_t i = (size_t)bs * Dd + d;
    const int t = tdiff[b];
    const float nz = noise[i];
    tmpb[i] = (bf16)(aligned[i] * salpha[b] + nz * sbeta[b] + temb[(size_t)t * Dd + d]);
    noise_out[i] = nz;
}

// ---------------- pooled 2-class heads ----------------
__device__ inline void pool_reduce_write(float m, const float* __restrict__ Wout,
                                         const float* __restrict__ bout,
                                         float* __restrict__ outp, int b,
                                         float* r0, float* r1)
{
    float v0 = m * Wout[threadIdx.x];
    float v1 = m * Wout[Dd + threadIdx.x];
#pragma unroll
    for (int off = 32; off; off >>= 1) { v0 += __shfl_down(v0, off); v1 += __shfl_down(v1, off); }
    const int lane = threadIdx.x & 63, wv = threadIdx.x >> 6;
    if (lane == 0) { r0[wv] = v0; r1[wv] = v1; }
    __syncthreads();
    if (threadIdx.x == 0) {
        outp[b * 2 + 0] = r0[0] + r0[1] + r0[2] + r0[3] + bout[0];
        outp[b * 2 + 1] = r1[0] + r1[1] + r1[2] + r1[3] + bout[1];
    }
}

__global__ __launch_bounds__(256) void pool_x_kernel(
    const float* __restrict__ x, const float* __restrict__ Wout,
    const float* __restrict__ bout, float* __restrict__ outp)
{
    __shared__ float r0[4], r1[4];
    const int b = blockIdx.x, d = threadIdx.x;
    float m = -INFINITY;
    for (int s = 0; s < Ss; ++s) m = fmaxf(m, x[((size_t)b * Ss + s) * Dd + d]);
    pool_reduce_write(m, Wout, bout, outp, b, r0, r1);
}

__global__ __launch_bounds__(256) void gen_pool_kernel(
    const float* __restrict__ aligned, const float* __restrict__ noise,
    const float* __restrict__ pred, const float* __restrict__ Wout,
    const float* __restrict__ bout, float* __restrict__ outp)
{
    __shared__ float r0[4], r1[4];
    const int b = blockIdx.x, d = threadIdx.x;
    float m = -INFINITY;
    for (int s = 0; s < Ss; ++s) {
        const size_t i = ((size_t)b * Ss + s) * Dd + d;
        m = fmaxf(m, aligned[i] + noise[i] - pred[i]);
    }
    pool_reduce_write(m, Wout, bout, outp, b, r0, r1);
}

// ---------------- host ----------------
extern "C" void kernel_launch(void* const* d_in, const int* in_sizes, int n_in,
                              void* d_out, int out_size, void* d_ws, size_t ws_size,
                              hipStream_t stream)
{
    const int*   seqs  = (const int*)d_in[0];
    const int*   tdiff = (const int*)d_in[5];
    const float* noise = (const float*)d_in[6];
    const float* emb   = (const float*)d_in[7];
    const float* Wih   = (const float*)d_in[8];
    const float* Whh   = (const float*)d_in[9];
    const float* bih   = (const float*)d_in[10];
    const float* bhh   = (const float*)d_in[11];
    const float* Whk   = (const float*)d_in[12];
    const float* bhk   = (const float*)d_in[13];
    const float* W1    = (const float*)d_in[14];
    const float* b1    = (const float*)d_in[15];
    const float* W2    = (const float*)d_in[16];
    const float* b2    = (const float*)d_in[17];
    const float* Wdiff = (const float*)d_in[18];
    const float* bdiff = (const float*)d_in[19];
    const float* temb  = (const float*)d_in[20];
    const float* Wout  = (const float*)d_in[21];
    const float* bout  = (const float*)d_in[22];

    float* outp = (float*)d_out;
    char*  wsb  = (char*)d_ws;

    bf16*  gatesb  = (bf16*) (wsb + OFFB_GATES);
    bf16*  embb    = (bf16*) (wsb + OFFB_EMBB);
    float* aligned = (float*)(wsb + OFFB_ALIGNED);
    bf16*  catb    = (bf16*) (wsb + OFFB_CAT);
    bf16*  tmpb    = (bf16*) (wsb + OFFB_TMPB);
    float* H1      = (float*)(wsb + OFFB_H1);
    float* attnw   = (float*)(wsb + OFFB_ATTNW);
    float* x       = (float*)(wsb + OFFB_X);
    bf16*  xb      = (bf16*) (wsb + OFFB_XB);
    bf16*  rnnb    = (bf16*) (wsb + OFFB_RNNB);
    float* wbuf    = (float*)(wsb + OFFB_W);
    bf16*  Wihb    = (bf16*) (wsb + OFFB_WIHB);
    bf16*  Whhb    = (bf16*) (wsb + OFFB_WHHB);
    bf16*  Whkb    = (bf16*) (wsb + OFFB_WHKB);
    bf16*  W1b     = (bf16*) (wsb + OFFB_W1B);
    bf16*  WdTb    = (bf16*) (wsb + OFFB_WDTB);
    float* salpha  = (float*)(wsb + OFFB_SALPHA);
    float* sbeta   = (float*)(wsb + OFFB_SBETA);
    float* pbias   = (float*)(wsb + OFFB_PBIAS);
    bf16*  Whhf    = (bf16*) (wsb + OFFB_WHHF);

    float* pred_out  = outp + 1024;                        // (B,S,D)
    float* noise_out = outp + 1024 + (size_t)Bb * Ss * Dd; // (B,S,D)

    alpha_kernel<<<1, 256, 0, stream>>>(tdiff, salpha, sbeta);

    cvt_weights_kernel<<<609, 256, 0, stream>>>(Wih, Whh, Whk, W1, bih, bhh,
                                                Wihb, Whhb, Whkb, W1b, pbias);
    whhf_repack_kernel<<<128, 256, 0, stream>>>(Whhb, Whhf);
    transpose_cvt_kernel<<<dim3(8, 8), 256, 0, stream>>>(Wdiff, WdTb, 256, 256);
    cvt_emb_kernel<<<5001, 256, 0, stream>>>(emb, embb, 20001 * 64);

    // x = emb[seqs].sum(axis=2)  (fp32 + bf16), bf16 gather
    embed_kernel<<<Bb * Ss, 128, 0, stream>>>(seqs, (const unsigned*)embb, x, xb);

    // pool_x head (only needs x)
    pool_x_kernel<<<Bb, 256, 0, stream>>>(x, Wout, bout, outp);

    // gates_pre = x @ Wih^T + (bih+bhh), permuted cols, bf16 out
    mfma_gemm<128, 128, 0, 1><<<dim3(100, 8), 256, 0, stream>>>(
        xb, 256, Wihb, 256, pbias, nullptr, gatesb, 1024, 256);

    // LSTM recurrence: one launch, 16 independent blocks, 16 waves each
    lstm_rec<<<16, 1024, 0, stream>>>(Whhf, gatesb, rnnb);

    // w = rnn @ Whk^T + bhk : (12800 x 256), K=256
    mfma_gemm<128, 128, 0, 0><<<dim3(100, 2), 256, 0, stream>>>(
        rnnb, 256, Whkb, 256, bhk, nullptr, wbuf, 256, 256);

    // attention MLP
    cat_build_kernel<<<Bb * (Ss - 1), 256, 0, stream>>>(x, wbuf, catb);
    mfma_gemm<128, 64, 1, 0><<<dim3(98, 1), 256, 0, stream>>>(
        catb, 512, W1b, 512, b1, nullptr, H1, 64, 512);
    attn2_kernel<<<(Bb * (Ss - 1)) / 4, 256, 0, stream>>>(H1, W2, b2, attnw);
    attn_apply_kernel<<<Bb * Ss, 256, 0, stream>>>(x, wbuf, attnw, aligned);

    // diffusion elementwise (+ noise passthrough fused)
    diff_kernel<<<Bb * Ss, 256, 0, stream>>>(aligned, noise, temb, tdiff,
                                             salpha, sbeta, tmpb, noise_out);

    // predicted_noise = tmp @ Wdiff + bdiff -> d_out
    mfma_gemm<128, 128, 0, 0><<<dim3(100, 2), 256, 0, stream>>>(
        tmpb, 256, WdTb, 256, bdiff, nullptr, pred_out, 256, 256);

    // gen_pool head: max_s(aligned + noise - pred) @ Wout^T + bout
    gen_pool_kernel<<<Bb, 256, 0, stream>>>(aligned, noise, pred_out, Wout, bout, outp + 512);
}